// Round 1
// baseline (291.892 us; speedup 1.0000x reference)
//
#include <hip/hip_runtime.h>
#include <cstdint>
#include <cmath>

#define LN_EPS 1e-6f

// ---- workspace layout (float offsets) ----
#define N_QCH 24u                      // q partial chunks (32 c each)
#define O_QPART 0u                     // [24][3072]
#define O_Q     73728u                 // [3072] scaled q
#define O_WK    76800u                 // wk_eff [768][12]
#define O_BKE   86016u                 // [12] (pad to 16)
#define O_PHP   86032u                 // ph partials [32][96][768]
#define N_SC    32
#define O_PH    (O_PHP + 2359296u)     // [96][768]
#define O_CTXP  (O_PH + 73728u)        // ctx partials [12][8][3072]
#define N_CCH   12
#define O_CTX   (O_CTXP + 294912u)     // [8][3072]
#define O_OUTP  (O_CTX + 24576u)       // out partials [48][8][768]
#define N_ICH   48

__device__ __forceinline__ float waveReduceSum(float v) {
#pragma unroll
    for (int o = 32; o >= 1; o >>= 1) v += __shfl_xor(v, o, 64);
    return v;
}
__device__ __forceinline__ float waveReduceMax(float v) {
#pragma unroll
    for (int o = 32; o >= 1; o >>= 1) v = fmaxf(v, __shfl_xor(v, o, 64));
    return v;
}

// K1: q partials: q_part[ch][h*256+d] = sum_{c in chunk} pq[c]*Wq[c, h*256+d]
__global__ __launch_bounds__(256) void k1_qpart(const float* __restrict__ pq,
                                                const float* __restrict__ Wq,
                                                float* __restrict__ ws) {
    int h = blockIdx.x % 12;
    int ch = blockIdx.x / 12;          // 24 chunks of 32 c
    int tid = threadIdx.x;
    int col = h * 256 + tid;
    int c0 = ch * 32;
    float acc = 0.f;
#pragma unroll 8
    for (int i = 0; i < 32; ++i) {
        int c = c0 + i;
        acc += pq[c] * Wq[c * 3072 + col];
    }
    ws[O_QPART + ch * 3072 + col] = acc;
}

// K1b: reduce q partials, add bq, apply scale * softplus(per_dim_scale)
__global__ __launch_bounds__(256) void k1b_qreduce(const float* __restrict__ bq,
                                                   const float* __restrict__ pds,
                                                   float* __restrict__ ws) {
    int j = blockIdx.x * 256 + threadIdx.x;   // < 3072
    float acc = bq[j];
#pragma unroll
    for (unsigned ch = 0; ch < N_QCH; ++ch) acc += ws[O_QPART + ch * 3072 + j];
    float x = pds[j & 255];
    float sp = (x > 20.f) ? x : log1pf(expf(x));
    const float scale = 1.442695041f / 16.0f;  // r_softplus_0 / sqrt(256)
    ws[O_Q + j] = acc * scale * sp;
}

// K2: wk_eff[c][h] = sum_d Wk[c, h*256+d]*q[h,d];  bk_eff[h] = sum_d bk[h*256+d]*q[h,d]
__global__ __launch_bounds__(256) void k2_wkeff(const float* __restrict__ Wk,
                                                const float* __restrict__ bk,
                                                float* __restrict__ ws) {
    __shared__ float sh[4];
    int tid = threadIdx.x;
    int blk = blockIdx.x;
    float v;
    if (blk < 9216) {
        int c = blk / 12, h = blk % 12;
        v = Wk[c * 3072 + h * 256 + tid] * ws[O_Q + h * 256 + tid];
    } else {
        int h = blk - 9216;
        v = bk[h * 256 + tid] * ws[O_Q + h * 256 + tid];
    }
    v = waveReduceSum(v);
    if ((tid & 63) == 0) sh[tid >> 6] = v;
    __syncthreads();
    if (tid == 0) {
        float s = sh[0] + sh[1] + sh[2] + sh[3];
        if (blk < 9216) {
            int c = blk / 12, h = blk % 12;
            ws[O_WK + c * 12 + h] = s;
        } else {
            ws[O_BKE + (blk - 9216)] = s;
        }
    }
}

// K3: logits[b,h,s] = hidden[b,s,:] . wk_eff[:,h] + bk_eff[h]
// block = (b, s-tile of 64 rows). LDS transpose [c][row] (stride 65), lane = row.
__global__ __launch_bounds__(256) void k3_logits(const float* __restrict__ hidden,
                                                 const float* __restrict__ ws,
                                                 float* __restrict__ attn) {
    __shared__ float tile[192 * 65];   // 49.9 KB
    __shared__ float red[48 * 64];     // 12 KB
    int blk = blockIdx.x;              // 512 = 8 b * 64 tiles
    int b = blk >> 6;
    int s0 = (blk & 63) * 64;
    const float* hb = hidden + (size_t)(b * 4096 + s0) * 768;
    int tid = threadIdx.x;
    int w = tid >> 6, lane = tid & 63;
    float acc[12];
#pragma unroll
    for (int h = 0; h < 12; ++h) acc[h] = 0.f;
    const float* wk = ws + O_WK;
    for (int ch = 0; ch < 4; ++ch) {
        int cbase = ch * 192;
        __syncthreads();
        // stage 64 rows x 192 c, transposed into LDS
#pragma unroll
        for (int it = 0; it < 12; ++it) {
            int idx = it * 256 + tid;             // < 3072 float4 slots
            int r = idx / 48, cc4 = idx % 48;
            const float4 v = *reinterpret_cast<const float4*>(hb + r * 768 + cbase + cc4 * 4);
            int c0 = cc4 * 4;
            tile[(c0 + 0) * 65 + r] = v.x;
            tile[(c0 + 1) * 65 + r] = v.y;
            tile[(c0 + 2) * 65 + r] = v.z;
            tile[(c0 + 3) * 65 + r] = v.w;
        }
        __syncthreads();
        // wave w covers chunk-local c in [w*48, w*48+48)
#pragma unroll 4
        for (int j = 0; j < 48; ++j) {
            int cc = w * 48 + j;
            float x = tile[cc * 65 + lane];
            const float4* wr = reinterpret_cast<const float4*>(wk + (cbase + cc) * 12);
            float4 w0 = wr[0], w1 = wr[1], w2 = wr[2];
            acc[0] += x * w0.x;  acc[1] += x * w0.y;  acc[2]  += x * w0.z;  acc[3]  += x * w0.w;
            acc[4] += x * w1.x;  acc[5] += x * w1.y;  acc[6]  += x * w1.z;  acc[7]  += x * w1.w;
            acc[8] += x * w2.x;  acc[9] += x * w2.y;  acc[10] += x * w2.z;  acc[11] += x * w2.w;
        }
    }
    __syncthreads();
#pragma unroll
    for (int h = 0; h < 12; ++h) red[(w * 12 + h) * 64 + lane] = acc[h];
    __syncthreads();
    const float* bke = ws + O_BKE;
    for (int idx = tid; idx < 768; idx += 256) {
        int h = idx / 64, r = idx & 63;
        float v = red[(0 + h) * 64 + r] + red[(12 + h) * 64 + r] +
                  red[(24 + h) * 64 + r] + red[(36 + h) * 64 + r] + bke[h];
        attn[(size_t)(b * 12 + h) * 4096 + s0 + r] = v;
    }
}

// K4: softmax over s=4096, in place on the attn region of d_out
__global__ __launch_bounds__(256) void k4_softmax(float* __restrict__ attn) {
    __shared__ float sh[4];
    int row = blockIdx.x;              // 96 = 8*12
    float* base = attn + (size_t)row * 4096;
    int tid = threadIdx.x;
    float4 x[4];
#pragma unroll
    for (int t = 0; t < 4; ++t) x[t] = reinterpret_cast<float4*>(base)[t * 256 + tid];
    float m = -1e30f;
#pragma unroll
    for (int t = 0; t < 4; ++t) {
        m = fmaxf(m, fmaxf(fmaxf(x[t].x, x[t].y), fmaxf(x[t].z, x[t].w)));
    }
    m = waveReduceMax(m);
    if ((tid & 63) == 0) sh[tid >> 6] = m;
    __syncthreads();
    m = fmaxf(fmaxf(sh[0], sh[1]), fmaxf(sh[2], sh[3]));
    __syncthreads();
    float s = 0.f;
#pragma unroll
    for (int t = 0; t < 4; ++t) {
        x[t].x = expf(x[t].x - m); x[t].y = expf(x[t].y - m);
        x[t].z = expf(x[t].z - m); x[t].w = expf(x[t].w - m);
        s += x[t].x + x[t].y + x[t].z + x[t].w;
    }
    s = waveReduceSum(s);
    if ((tid & 63) == 0) sh[tid >> 6] = s;
    __syncthreads();
    s = sh[0] + sh[1] + sh[2] + sh[3];
    float inv = 1.0f / s;
#pragma unroll
    for (int t = 0; t < 4; ++t) {
        x[t].x *= inv; x[t].y *= inv; x[t].z *= inv; x[t].w *= inv;
        reinterpret_cast<float4*>(base)[t * 256 + tid] = x[t];
    }
}

// K5: ph partials: ph_part[sc][b*12+h][c] = sum_{s in chunk} attn[b,h,s]*hidden[b,s,c]
__global__ __launch_bounds__(256) void k5_phpart(const float* __restrict__ hidden,
                                                 const float* __restrict__ attn,
                                                 float* __restrict__ ws) {
    int blk = blockIdx.x;              // 768 = 8 b * 3 ct * 32 sc
    int sc = blk & 31;
    int ct = (blk >> 5) % 3;
    int b = blk / 96;
    int tid = threadIdx.x;
    int c = ct * 256 + tid;
    int s0 = sc * 128;
    const float* hb = hidden + (size_t)(b * 4096 + s0) * 768 + c;
    const float* ab = attn + (size_t)b * 49152 + s0;
    float acc[12];
#pragma unroll
    for (int h = 0; h < 12; ++h) acc[h] = 0.f;
    for (int g = 0; g < 32; ++g) {     // 4 s per group
        float x0 = hb[(g * 4 + 0) * 768];
        float x1 = hb[(g * 4 + 1) * 768];
        float x2 = hb[(g * 4 + 2) * 768];
        float x3 = hb[(g * 4 + 3) * 768];
#pragma unroll
        for (int h = 0; h < 12; ++h) {
            const float4 a = *reinterpret_cast<const float4*>(ab + h * 4096 + g * 4);
            acc[h] += a.x * x0 + a.y * x1 + a.z * x2 + a.w * x3;
        }
    }
    float* php = ws + O_PHP;
#pragma unroll
    for (int h = 0; h < 12; ++h)
        php[(size_t)(sc * 96 + b * 12 + h) * 768 + c] = acc[h];
}

// K6: reduce ph partials over the 32 s-chunks
__global__ __launch_bounds__(256) void k6_phreduce(float* __restrict__ ws) {
    int gid = blockIdx.x * 256 + threadIdx.x;   // < 73728
    const float* php = ws + O_PHP;
    float s = 0.f;
#pragma unroll
    for (int sc = 0; sc < N_SC; ++sc) s += php[(size_t)sc * 73728 + gid];
    ws[O_PH + gid] = s;
}

// K7: ctx partials: ctx_part[cch][b][j] = sum_{c in chunk} ph[b, h(j), c] * Wv[c, j]
__global__ __launch_bounds__(256) void k7_ctxpart(const float* __restrict__ Wv,
                                                  float* __restrict__ ws) {
    int blk = blockIdx.x;              // 144 = 12 jt * 12 cch
    int jt = blk % 12, cch = blk / 12;
    int tid = threadIdx.x;
    int j = jt * 256 + tid;
    int h = jt;                        // j-tile of 256 aligns with heads
    const float* ph = ws + O_PH;
    float acc[8];
#pragma unroll
    for (int b = 0; b < 8; ++b) acc[b] = 0.f;
    for (int cc = 0; cc < 64; ++cc) {
        int c = cch * 64 + cc;
        float wv = Wv[(size_t)c * 3072 + j];
#pragma unroll
        for (int b = 0; b < 8; ++b) acc[b] += ph[(b * 12 + h) * 768 + c] * wv;
    }
#pragma unroll
    for (int b = 0; b < 8; ++b)
        ws[O_CTXP + (size_t)(cch * 8 + b) * 3072 + j] = acc[b];
}

// K7b: ctx[b][i] = sum_cch ctx_part + bv[i]
__global__ __launch_bounds__(256) void k7b_ctxreduce(const float* __restrict__ bv,
                                                     float* __restrict__ ws) {
    int gid = blockIdx.x * 256 + threadIdx.x;   // < 24576
    int b = gid / 3072, i = gid % 3072;
    float s = bv[i];
#pragma unroll
    for (int cch = 0; cch < N_CCH; ++cch) s += ws[O_CTXP + (size_t)(cch * 8 + b) * 3072 + i];
    ws[O_CTX + gid] = s;
}

// K8: out partials: out_part[ich][b][j] = sum_{i in chunk} ctx[b][i]*Wp[i,j]
__global__ __launch_bounds__(256) void k8_outpart(const float* __restrict__ Wp,
                                                  float* __restrict__ ws) {
    int blk = blockIdx.x;              // 144 = 3 jt * 48 ich
    int jt = blk % 3, ich = blk / 3;
    int tid = threadIdx.x;
    int j = jt * 256 + tid;
    const float* ctx = ws + O_CTX;
    float acc[8];
#pragma unroll
    for (int b = 0; b < 8; ++b) acc[b] = 0.f;
    for (int ii = 0; ii < 64; ++ii) {
        int i = ich * 64 + ii;
        float wp = Wp[(size_t)i * 768 + j];
#pragma unroll
        for (int b = 0; b < 8; ++b) acc[b] += ctx[b * 3072 + i] * wp;
    }
#pragma unroll
    for (int b = 0; b < 8; ++b)
        ws[O_OUTP + (size_t)(ich * 8 + b) * 768 + j] = acc[b];
}

// K9: reduce out partials + bp, layernorm, write pooled
__global__ __launch_bounds__(256) void k9_ln(const float* __restrict__ bp,
                                             const float* __restrict__ ln_w,
                                             const float* __restrict__ ln_b,
                                             const float* __restrict__ ws,
                                             float* __restrict__ pooled) {
    __shared__ float sh[8];
    int b = blockIdx.x, tid = threadIdx.x;
    const float* op = ws + O_OUTP;
    float vals[3];
    float lsum = 0.f, lsq = 0.f;
#pragma unroll
    for (int t = 0; t < 3; ++t) {
        int j = t * 256 + tid;
        float v = bp[j];
#pragma unroll
        for (int ich = 0; ich < N_ICH; ++ich) v += op[(size_t)(ich * 8 + b) * 768 + j];
        vals[t] = v; lsum += v; lsq += v * v;
    }
    lsum = waveReduceSum(lsum);
    lsq = waveReduceSum(lsq);
    if ((tid & 63) == 0) { sh[tid >> 6] = lsum; sh[4 + (tid >> 6)] = lsq; }
    __syncthreads();
    float mean = (sh[0] + sh[1] + sh[2] + sh[3]) * (1.f / 768.f);
    float var = (sh[4] + sh[5] + sh[6] + sh[7]) * (1.f / 768.f) - mean * mean;
    float inv = rsqrtf(var + LN_EPS);
#pragma unroll
    for (int t = 0; t < 3; ++t) {
        int j = t * 256 + tid;
        pooled[b * 768 + j] = (vals[t] - mean) * inv * (ln_w[j] + 1.f) + ln_b[j];
    }
}

extern "C" void kernel_launch(void* const* d_in, const int* in_sizes, int n_in,
                              void* d_out, int out_size, void* d_ws, size_t ws_size,
                              hipStream_t stream) {
    const float* hidden = (const float*)d_in[0];
    const float* pq     = (const float*)d_in[1];
    const float* Wq     = (const float*)d_in[2];
    const float* bq     = (const float*)d_in[3];
    const float* Wk     = (const float*)d_in[4];
    const float* bk     = (const float*)d_in[5];
    const float* Wv     = (const float*)d_in[6];
    const float* bv     = (const float*)d_in[7];
    const float* Wp     = (const float*)d_in[8];
    const float* bp     = (const float*)d_in[9];
    const float* pds    = (const float*)d_in[10];
    const float* ln_w   = (const float*)d_in[11];
    const float* ln_b   = (const float*)d_in[12];
    float* out = (float*)d_out;
    float* ws  = (float*)d_ws;
    float* pooled = out;          // (8,1,768) = 6144 floats
    float* attn   = out + 6144;   // (8,12,1,4096) = 393216 floats

    k1_qpart   <<<288, 256, 0, stream>>>(pq, Wq, ws);
    k1b_qreduce<<<12, 256, 0, stream>>>(bq, pds, ws);
    k2_wkeff   <<<9228, 256, 0, stream>>>(Wk, bk, ws);
    k3_logits  <<<512, 256, 0, stream>>>(hidden, ws, attn);
    k4_softmax <<<96, 256, 0, stream>>>(attn);
    k5_phpart  <<<768, 256, 0, stream>>>(hidden, attn, ws);
    k6_phreduce<<<288, 256, 0, stream>>>(ws);
    k7_ctxpart <<<144, 256, 0, stream>>>(Wv, ws);
    k7b_ctxreduce<<<96, 256, 0, stream>>>(bv, ws);
    k8_outpart <<<144, 256, 0, stream>>>(Wp, ws);
    k9_ln      <<<8, 256, 0, stream>>>(bp, ln_w, ln_b, ws, pooled);
}

// Round 2
// 273.155 us; speedup vs baseline: 1.0686x; 1.0686x over previous
//
#include <hip/hip_runtime.h>
#include <cstdint>
#include <cmath>

#define LN_EPS 1e-6f

// ---- workspace layout (float offsets) ----
#define N_QCH 24u                      // q partial chunks (32 c each)
#define O_QPART 0u                     // [24][3072]
#define O_Q     73728u                 // [3072] scaled q
#define O_WK    76800u                 // wk_eff [768][12]
#define O_BKE   86016u                 // [12] (pad to 16) -- unused (softmax-invariant)
#define O_PHP   86032u                 // ph partials [32][96][768]  (aliased: plog [2][96][4096])
#define O_PLOG  O_PHP                  // partial logits, consumed by k4 before k5 overwrites
#define N_SC    32
#define O_PH    (O_PHP + 2359296u)     // [96][768]
#define O_CTXP  (O_PH + 73728u)        // ctx partials [12][8][3072]
#define N_CCH   12
#define O_CTX   (O_CTXP + 294912u)     // [8][3072]
#define O_OUTP  (O_CTX + 24576u)       // out partials [48][8][768]
#define N_ICH   48

__device__ __forceinline__ float waveReduceSum(float v) {
#pragma unroll
    for (int o = 32; o >= 1; o >>= 1) v += __shfl_xor(v, o, 64);
    return v;
}
__device__ __forceinline__ float waveReduceMax(float v) {
#pragma unroll
    for (int o = 32; o >= 1; o >>= 1) v = fmaxf(v, __shfl_xor(v, o, 64));
    return v;
}

// K1: q partials: q_part[ch][h*256+d] = sum_{c in chunk} pq[c]*Wq[c, h*256+d]
__global__ __launch_bounds__(256) void k1_qpart(const float* __restrict__ pq,
                                                const float* __restrict__ Wq,
                                                float* __restrict__ ws) {
    int h = blockIdx.x % 12;
    int ch = blockIdx.x / 12;          // 24 chunks of 32 c
    int tid = threadIdx.x;
    int col = h * 256 + tid;
    int c0 = ch * 32;
    float acc = 0.f;
#pragma unroll 8
    for (int i = 0; i < 32; ++i) {
        int c = c0 + i;
        acc += pq[c] * Wq[c * 3072 + col];
    }
    ws[O_QPART + ch * 3072 + col] = acc;
}

// K1b: reduce q partials, add bq, apply scale * softplus(per_dim_scale)
__global__ __launch_bounds__(256) void k1b_qreduce(const float* __restrict__ bq,
                                                   const float* __restrict__ pds,
                                                   float* __restrict__ ws) {
    int j = blockIdx.x * 256 + threadIdx.x;   // < 3072
    float acc = bq[j];
#pragma unroll
    for (unsigned ch = 0; ch < N_QCH; ++ch) acc += ws[O_QPART + ch * 3072 + j];
    float x = pds[j & 255];
    float sp = (x > 20.f) ? x : log1pf(expf(x));
    const float scale = 1.442695041f / 16.0f;  // r_softplus_0 / sqrt(256)
    ws[O_Q + j] = acc * scale * sp;
}

// K2: wk_eff[c][h] = sum_d Wk[c, h*256+d]*q[h,d]
// (bias bk folds to a per-row constant in the logits -> softmax-invariant -> dropped)
__global__ __launch_bounds__(256) void k2_wkeff(const float* __restrict__ Wk,
                                                float* __restrict__ ws) {
    __shared__ float sh[4];
    int tid = threadIdx.x;
    int blk = blockIdx.x;              // 9216 = 768 c * 12 h
    int c = blk / 12, h = blk % 12;
    float v = Wk[c * 3072 + h * 256 + tid] * ws[O_Q + h * 256 + tid];
    v = waveReduceSum(v);
    if ((tid & 63) == 0) sh[tid >> 6] = v;
    __syncthreads();
    if (tid == 0) ws[O_WK + c * 12 + h] = sh[0] + sh[1] + sh[2] + sh[3];
}

// K3: partial logits. block = (b, s-tile of 64 rows, c-half of 384).
// XOR-swizzled float4 LDS tile: store tile4[r*24 + (j^(r&7))]; lane=row reads are
// conflict-free (bank set = (j&7)^(lane&7) -> exactly 8 lanes/set).
// wk_eff slice staged in LDS -> uniform-address broadcast reads.
__global__ __launch_bounds__(256) void k3_logits(const float* __restrict__ hidden,
                                                 float* __restrict__ ws) {
    __shared__ float4 tile4[1536];     // 24 KB: 64 rows x 24 float4 (96 c), swizzled
    __shared__ float4 wkb4[288];       // 4.5 KB: 96 c x 12 h
    int blk = blockIdx.x;              // 1024 = 8 b * 64 stiles * 2 halves
    int half = blk & 1;
    int st = (blk >> 1) & 63;
    int b = blk >> 7;
    int s0 = st * 64;
    const float* hb = hidden + (size_t)(b * 4096 + s0) * 768;
    const float4* wkg4 = reinterpret_cast<const float4*>(ws + O_WK);
    int tid = threadIdx.x;
    int w = tid >> 6, lane = tid & 63;
    float acc[12];
#pragma unroll
    for (int h = 0; h < 12; ++h) acc[h] = 0.f;

    for (int ch = 0; ch < 4; ++ch) {
        int cbase = half * 384 + ch * 96;
        __syncthreads();
        // stage wk slice: 96 c x 12 h = 288 float4
        for (int i = tid; i < 288; i += 256) wkb4[i] = wkg4[cbase * 3 + i];
        // stage hidden tile: 64 rows x 24 float4, swizzled store
#pragma unroll
        for (int it = 0; it < 6; ++it) {
            int idx = it * 256 + tid;
            int r = idx / 24, j = idx % 24;
            const float4 v = *reinterpret_cast<const float4*>(hb + r * 768 + cbase + j * 4);
            tile4[r * 24 + (j ^ (r & 7))] = v;
        }
        __syncthreads();
        // wave w covers j in [w*6, w*6+6)
#pragma unroll
        for (int jj = 0; jj < 6; ++jj) {
            int jcol = w * 6 + jj;
            float4 x = tile4[lane * 24 + (jcol ^ (lane & 7))];
            const float4* wr = &wkb4[jcol * 12];
            float xc[4] = {x.x, x.y, x.z, x.w};
#pragma unroll
            for (int cc = 0; cc < 4; ++cc) {
                float4 w0 = wr[cc * 3 + 0], w1 = wr[cc * 3 + 1], w2 = wr[cc * 3 + 2];
                acc[0] += xc[cc] * w0.x;  acc[1] += xc[cc] * w0.y;  acc[2]  += xc[cc] * w0.z;  acc[3]  += xc[cc] * w0.w;
                acc[4] += xc[cc] * w1.x;  acc[5] += xc[cc] * w1.y;  acc[6]  += xc[cc] * w1.z;  acc[7]  += xc[cc] * w1.w;
                acc[8] += xc[cc] * w2.x;  acc[9] += xc[cc] * w2.y;  acc[10] += xc[cc] * w2.z;  acc[11] += xc[cc] * w2.w;
            }
        }
    }
    __syncthreads();
    float* red = reinterpret_cast<float*>(tile4);   // alias tile (3072 <= 6144 floats)
#pragma unroll
    for (int h = 0; h < 12; ++h) red[(w * 12 + h) * 64 + lane] = acc[h];
    __syncthreads();
    float* plog = ws + O_PLOG;
    for (int idx = tid; idx < 768; idx += 256) {
        int h = idx / 64, r = idx & 63;
        float v = red[(0 + h) * 64 + r] + red[(12 + h) * 64 + r] +
                  red[(24 + h) * 64 + r] + red[(36 + h) * 64 + r];
        plog[(size_t)half * 393216 + (size_t)(b * 12 + h) * 4096 + s0 + r] = v;
    }
}

// K4: sum the two c-half partials, softmax over s=4096, write attn to d_out
__global__ __launch_bounds__(256) void k4_softmax(const float* __restrict__ ws,
                                                  float* __restrict__ attn) {
    __shared__ float sh[4];
    int row = blockIdx.x;              // 96 = 8*12
    const float4* p0 = reinterpret_cast<const float4*>(ws + O_PLOG + (size_t)row * 4096);
    const float4* p1 = reinterpret_cast<const float4*>(ws + O_PLOG + 393216u + (size_t)row * 4096);
    float* base = attn + (size_t)row * 4096;
    int tid = threadIdx.x;
    float4 x[4];
#pragma unroll
    for (int t = 0; t < 4; ++t) {
        float4 a = p0[t * 256 + tid], c = p1[t * 256 + tid];
        x[t].x = a.x + c.x; x[t].y = a.y + c.y; x[t].z = a.z + c.z; x[t].w = a.w + c.w;
    }
    float m = -1e30f;
#pragma unroll
    for (int t = 0; t < 4; ++t) {
        m = fmaxf(m, fmaxf(fmaxf(x[t].x, x[t].y), fmaxf(x[t].z, x[t].w)));
    }
    m = waveReduceMax(m);
    if ((tid & 63) == 0) sh[tid >> 6] = m;
    __syncthreads();
    m = fmaxf(fmaxf(sh[0], sh[1]), fmaxf(sh[2], sh[3]));
    __syncthreads();
    float s = 0.f;
#pragma unroll
    for (int t = 0; t < 4; ++t) {
        x[t].x = expf(x[t].x - m); x[t].y = expf(x[t].y - m);
        x[t].z = expf(x[t].z - m); x[t].w = expf(x[t].w - m);
        s += x[t].x + x[t].y + x[t].z + x[t].w;
    }
    s = waveReduceSum(s);
    if ((tid & 63) == 0) sh[tid >> 6] = s;
    __syncthreads();
    s = sh[0] + sh[1] + sh[2] + sh[3];
    float inv = 1.0f / s;
#pragma unroll
    for (int t = 0; t < 4; ++t) {
        x[t].x *= inv; x[t].y *= inv; x[t].z *= inv; x[t].w *= inv;
        reinterpret_cast<float4*>(base)[t * 256 + tid] = x[t];
    }
}

// K5: ph partials: ph_part[sc][b*12+h][c] = sum_{s in chunk} attn[b,h,s]*hidden[b,s,c]
__global__ __launch_bounds__(256) void k5_phpart(const float* __restrict__ hidden,
                                                 const float* __restrict__ attn,
                                                 float* __restrict__ ws) {
    int blk = blockIdx.x;              // 768 = 8 b * 3 ct * 32 sc
    int sc = blk & 31;
    int ct = (blk >> 5) % 3;
    int b = blk / 96;
    int tid = threadIdx.x;
    int c = ct * 256 + tid;
    int s0 = sc * 128;
    const float* hb = hidden + (size_t)(b * 4096 + s0) * 768 + c;
    const float* ab = attn + (size_t)b * 49152 + s0;
    float acc[12];
#pragma unroll
    for (int h = 0; h < 12; ++h) acc[h] = 0.f;
    for (int g = 0; g < 32; ++g) {     // 4 s per group
        float x0 = hb[(g * 4 + 0) * 768];
        float x1 = hb[(g * 4 + 1) * 768];
        float x2 = hb[(g * 4 + 2) * 768];
        float x3 = hb[(g * 4 + 3) * 768];
#pragma unroll
        for (int h = 0; h < 12; ++h) {
            const float4 a = *reinterpret_cast<const float4*>(ab + h * 4096 + g * 4);
            acc[h] += a.x * x0 + a.y * x1 + a.z * x2 + a.w * x3;
        }
    }
    float* php = ws + O_PHP;
#pragma unroll
    for (int h = 0; h < 12; ++h)
        php[(size_t)(sc * 96 + b * 12 + h) * 768 + c] = acc[h];
}

// K6: reduce ph partials over the 32 s-chunks
__global__ __launch_bounds__(256) void k6_phreduce(float* __restrict__ ws) {
    int gid = blockIdx.x * 256 + threadIdx.x;   // < 73728
    const float* php = ws + O_PHP;
    float s = 0.f;
#pragma unroll
    for (int sc = 0; sc < N_SC; ++sc) s += php[(size_t)sc * 73728 + gid];
    ws[O_PH + gid] = s;
}

// K7: ctx partials: ctx_part[cch][b][j] = sum_{c in chunk} ph[b, h(j), c] * Wv[c, j]
__global__ __launch_bounds__(256) void k7_ctxpart(const float* __restrict__ Wv,
                                                  float* __restrict__ ws) {
    int blk = blockIdx.x;              // 144 = 12 jt * 12 cch
    int jt = blk % 12, cch = blk / 12;
    int tid = threadIdx.x;
    int j = jt * 256 + tid;
    int h = jt;                        // j-tile of 256 aligns with heads
    const float* ph = ws + O_PH;
    float acc[8];
#pragma unroll
    for (int b = 0; b < 8; ++b) acc[b] = 0.f;
    for (int cc = 0; cc < 64; ++cc) {
        int c = cch * 64 + cc;
        float wv = Wv[(size_t)c * 3072 + j];
#pragma unroll
        for (int b = 0; b < 8; ++b) acc[b] += ph[(b * 12 + h) * 768 + c] * wv;
    }
#pragma unroll
    for (int b = 0; b < 8; ++b)
        ws[O_CTXP + (size_t)(cch * 8 + b) * 3072 + j] = acc[b];
}

// K7b: ctx[b][i] = sum_cch ctx_part + bv[i]
__global__ __launch_bounds__(256) void k7b_ctxreduce(const float* __restrict__ bv,
                                                     float* __restrict__ ws) {
    int gid = blockIdx.x * 256 + threadIdx.x;   // < 24576
    int b = gid / 3072, i = gid % 3072;
    float s = bv[i];
#pragma unroll
    for (int cch = 0; cch < N_CCH; ++cch) s += ws[O_CTXP + (size_t)(cch * 8 + b) * 3072 + i];
    ws[O_CTX + gid] = s;
}

// K8: out partials: out_part[ich][b][j] = sum_{i in chunk} ctx[b][i]*Wp[i,j]
__global__ __launch_bounds__(256) void k8_outpart(const float* __restrict__ Wp,
                                                  float* __restrict__ ws) {
    int blk = blockIdx.x;              // 144 = 3 jt * 48 ich
    int jt = blk % 3, ich = blk / 3;
    int tid = threadIdx.x;
    int j = jt * 256 + tid;
    const float* ctx = ws + O_CTX;
    float acc[8];
#pragma unroll
    for (int b = 0; b < 8; ++b) acc[b] = 0.f;
    for (int ii = 0; ii < 64; ++ii) {
        int i = ich * 64 + ii;
        float wp = Wp[(size_t)i * 768 + j];
#pragma unroll
        for (int b = 0; b < 8; ++b) acc[b] += ctx[b * 3072 + i] * wp;
    }
#pragma unroll
    for (int b = 0; b < 8; ++b)
        ws[O_OUTP + (size_t)(ich * 8 + b) * 768 + j] = acc[b];
}

// K9: reduce out partials + bp, layernorm, write pooled
__global__ __launch_bounds__(256) void k9_ln(const float* __restrict__ bp,
                                             const float* __restrict__ ln_w,
                                             const float* __restrict__ ln_b,
                                             const float* __restrict__ ws,
                                             float* __restrict__ pooled) {
    __shared__ float sh[8];
    int b = blockIdx.x, tid = threadIdx.x;
    const float* op = ws + O_OUTP;
    float vals[3];
    float lsum = 0.f, lsq = 0.f;
#pragma unroll
    for (int t = 0; t < 3; ++t) {
        int j = t * 256 + tid;
        float v = bp[j];
#pragma unroll
        for (int ich = 0; ich < N_ICH; ++ich) v += op[(size_t)(ich * 8 + b) * 768 + j];
        vals[t] = v; lsum += v; lsq += v * v;
    }
    lsum = waveReduceSum(lsum);
    lsq = waveReduceSum(lsq);
    if ((tid & 63) == 0) { sh[tid >> 6] = lsum; sh[4 + (tid >> 6)] = lsq; }
    __syncthreads();
    float mean = (sh[0] + sh[1] + sh[2] + sh[3]) * (1.f / 768.f);
    float var = (sh[4] + sh[5] + sh[6] + sh[7]) * (1.f / 768.f) - mean * mean;
    float inv = rsqrtf(var + LN_EPS);
#pragma unroll
    for (int t = 0; t < 3; ++t) {
        int j = t * 256 + tid;
        pooled[b * 768 + j] = (vals[t] - mean) * inv * (ln_w[j] + 1.f) + ln_b[j];
    }
}

extern "C" void kernel_launch(void* const* d_in, const int* in_sizes, int n_in,
                              void* d_out, int out_size, void* d_ws, size_t ws_size,
                              hipStream_t stream) {
    const float* hidden = (const float*)d_in[0];
    const float* pq     = (const float*)d_in[1];
    const float* Wq     = (const float*)d_in[2];
    const float* bq     = (const float*)d_in[3];
    const float* Wk     = (const float*)d_in[4];
    const float* bv     = (const float*)d_in[7];
    const float* Wv     = (const float*)d_in[6];
    const float* Wp     = (const float*)d_in[8];
    const float* bp     = (const float*)d_in[9];
    const float* pds    = (const float*)d_in[10];
    const float* ln_w   = (const float*)d_in[11];
    const float* ln_b   = (const float*)d_in[12];
    float* out = (float*)d_out;
    float* ws  = (float*)d_ws;
    float* pooled = out;          // (8,1,768) = 6144 floats
    float* attn   = out + 6144;   // (8,12,1,4096) = 393216 floats

    k1_qpart   <<<288, 256, 0, stream>>>(pq, Wq, ws);
    k1b_qreduce<<<12, 256, 0, stream>>>(bq, pds, ws);
    k2_wkeff   <<<9216, 256, 0, stream>>>(Wk, ws);
    k3_logits  <<<1024, 256, 0, stream>>>(hidden, ws);
    k4_softmax <<<96, 256, 0, stream>>>(ws, attn);
    k5_phpart  <<<768, 256, 0, stream>>>(hidden, attn, ws);
    k6_phreduce<<<288, 256, 0, stream>>>(ws);
    k7_ctxpart <<<144, 256, 0, stream>>>(Wv, ws);
    k7b_ctxreduce<<<96, 256, 0, stream>>>(bv, ws);
    k8_outpart <<<144, 256, 0, stream>>>(Wp, ws);
    k9_ln      <<<8, 256, 0, stream>>>(bp, ln_w, ln_b, ws, pooled);
}